// Round 5
// baseline (597.895 us; speedup 1.0000x reference)
//
#include <hip/hip_runtime.h>
#include <hip/hip_bf16.h>
#include <math.h>

#define DIM 128

typedef __attribute__((ext_vector_type(8))) short bf16x8;
typedef __attribute__((ext_vector_type(4))) float f32x4;

__device__ __forceinline__ ushort f2bf(float f) {  // RTNE
  unsigned u = __float_as_uint(f);
  return (ushort)((u + 0x7FFFu + ((u >> 16) & 1u)) >> 16);
}
__device__ __forceinline__ float bf2f(ushort h) {
  return __uint_as_float(((unsigned)h) << 16);
}

// ---------------- degree histogram + per-edge rank ----------------
__global__ __launch_bounds__(256) void hist_rank_kernel(const int* __restrict__ dst,
                                                        unsigned* __restrict__ deg,
                                                        unsigned* __restrict__ rank, int E) {
  int gid = blockIdx.x * 256 + threadIdx.x;
  if (gid < E) rank[gid] = atomicAdd(&deg[dst[gid]], 1u);
}

// ---------------- two-level exclusive scan over deg (+ fused dinv) ----------------
__global__ __launch_bounds__(256) void scan_block_kernel(const unsigned* __restrict__ deg,
                                                         unsigned* __restrict__ excl,
                                                         unsigned* __restrict__ partial,
                                                         float* __restrict__ dinv, int N) {
  __shared__ unsigned s[256];
  int i = blockIdx.x * 256 + threadIdx.x;
  unsigned v = (i < N) ? deg[i] : 0u;
  if (i < N) dinv[i] = 1.0f / fmaxf((float)v, 1.0f);
  s[threadIdx.x] = v;
  __syncthreads();
#pragma unroll
  for (int d = 1; d < 256; d <<= 1) {
    unsigned t = (threadIdx.x >= d) ? s[threadIdx.x - d] : 0u;
    __syncthreads();
    s[threadIdx.x] += t;
    __syncthreads();
  }
  if (i < N) excl[i] = s[threadIdx.x] - v;
  if (threadIdx.x == 255) partial[blockIdx.x] = s[255];
}

__global__ __launch_bounds__(256) void scan_partials_kernel(unsigned* __restrict__ partial, int B) {
  __shared__ unsigned s[256];
  __shared__ unsigned carry;
  if (threadIdx.x == 0) carry = 0u;
  __syncthreads();
  for (int base = 0; base < B; base += 256) {
    int i = base + threadIdx.x;
    unsigned v = (i < B) ? partial[i] : 0u;
    s[threadIdx.x] = v;
    __syncthreads();
#pragma unroll
    for (int d = 1; d < 256; d <<= 1) {
      unsigned t = (threadIdx.x >= d) ? s[threadIdx.x - d] : 0u;
      __syncthreads();
      s[threadIdx.x] += t;
      __syncthreads();
    }
    if (i < B) partial[i] = carry + s[threadIdx.x] - v;
    __syncthreads();
    if (threadIdx.x == 0) carry += s[255];
    __syncthreads();
  }
}

__global__ __launch_bounds__(256) void add_offsets_kernel(const unsigned* __restrict__ excl,
                                                          const unsigned* __restrict__ partial,
                                                          unsigned* __restrict__ off, int N, int E) {
  int i = blockIdx.x * 256 + threadIdx.x;
  if (i < N) off[i] = excl[i] + partial[i >> 8];
  if (i == N) off[N] = (unsigned)E;
}

// ---------------- CSR fill: atomic-free ----------------
__global__ __launch_bounds__(256) void csr_fill_kernel(const int* __restrict__ src,
                                                       const int* __restrict__ dst,
                                                       const unsigned* __restrict__ rank,
                                                       const unsigned* __restrict__ off,
                                                       int* __restrict__ csr_src, int E) {
  int e = blockIdx.x * 256 + threadIdx.x;
  if (e >= E) return;
  csr_src[off[dst[e]] + rank[e]] = src[e];
}

// ---------------- fp32 -> bf16 cast (hi only; lo-activation path dropped) ----------------
__global__ __launch_bounds__(256) void cast_kernel(const float* __restrict__ x,
                                                   ushort* __restrict__ xh, long total) {
  long i = ((long)blockIdx.x * 256 + threadIdx.x) * 4;
  if (i >= total) return;
  float4 v = *(const float4*)(x + i);
  uint2 H;
  H.x = (unsigned)f2bf(v.x) | ((unsigned)f2bf(v.y) << 16);
  H.y = (unsigned)f2bf(v.z) | ((unsigned)f2bf(v.w) << 16);
  *(uint2*)(xh + i) = H;
}

// ---------------- W fp32 [k][n] -> transposed bf16 hi/lo tables [n][k] ----------------
__global__ __launch_bounds__(256) void wsplit_kernel(const float* __restrict__ W1l,
                                                     const float* __restrict__ W1r,
                                                     const float* __restrict__ W2l,
                                                     const float* __restrict__ W2r,
                                                     ushort* __restrict__ tabs) {
  int m = blockIdx.y;
  const float* W = (m == 0) ? W1l : (m == 1) ? W1r : (m == 2) ? W2l : W2r;
  ushort* H = tabs + (size_t)m * 32768;
  ushort* L = H + 16384;
  int idx = blockIdx.x * 256 + threadIdx.x;  // 0..16383
  int k = idx >> 7, n = idx & 127;
  float v = W[idx];
  ushort h = f2bf(v);
  H[n * DIM + k] = h;
  L[n * DIM + k] = f2bf(v - bf2f(h));
}

// ---------------- XCD-sharded column-sliced gather-aggregate ----------------
// slice = blockIdx.x & 3 covers bytes [64*slice, 64*slice+64) of each 256 B row.
// With round-robin block->XCD dispatch, XCD x serves only slice x&3 ->
// per-XCD L2 working set 25.6 MB -> 6.4 MB. csr_src streamed nontemporally.
// 16 lanes/node x 4 B (2 bf16), 16 nodes per 256-block, edge loop unrolled x4.
__global__ __launch_bounds__(256) void gather_slice_kernel(
    const ushort* __restrict__ featH, const int* __restrict__ csr_src,
    const unsigned* __restrict__ off, const float* __restrict__ dinv,
    ushort* __restrict__ aggH, ushort* __restrict__ aggL, int N) {
  const int slice = blockIdx.x & 3;
  const int group = blockIdx.x >> 2;
  const int node = group * 16 + (threadIdx.x >> 4);
  if (node >= N) return;
  const int lane = threadIdx.x & 15;
  const ushort* base = featH + slice * 32 + lane * 2;
  unsigned beg = off[node], end = off[node + 1];
  float a0 = 0.f, a1 = 0.f;
  unsigned e = beg;
  for (; e + 4 <= end; e += 4) {
    int s0 = __builtin_nontemporal_load(csr_src + e);
    int s1 = __builtin_nontemporal_load(csr_src + e + 1);
    int s2 = __builtin_nontemporal_load(csr_src + e + 2);
    int s3 = __builtin_nontemporal_load(csr_src + e + 3);
    unsigned v0 = *(const unsigned*)(base + (size_t)s0 * DIM);
    unsigned v1 = *(const unsigned*)(base + (size_t)s1 * DIM);
    unsigned v2 = *(const unsigned*)(base + (size_t)s2 * DIM);
    unsigned v3 = *(const unsigned*)(base + (size_t)s3 * DIM);
    a0 += __uint_as_float(v0 << 16); a1 += __uint_as_float(v0 & 0xFFFF0000u);
    a0 += __uint_as_float(v1 << 16); a1 += __uint_as_float(v1 & 0xFFFF0000u);
    a0 += __uint_as_float(v2 << 16); a1 += __uint_as_float(v2 & 0xFFFF0000u);
    a0 += __uint_as_float(v3 << 16); a1 += __uint_as_float(v3 & 0xFFFF0000u);
  }
  for (; e < end; ++e) {
    int s = __builtin_nontemporal_load(csr_src + e);
    unsigned v = *(const unsigned*)(base + (size_t)s * DIM);
    a0 += __uint_as_float(v << 16); a1 += __uint_as_float(v & 0xFFFF0000u);
  }
  float di = dinv[node];
  a0 *= di; a1 *= di;
  ushort h0 = f2bf(a0), h1 = f2bf(a1);
  ushort l0 = f2bf(a0 - bf2f(h0)), l1 = f2bf(a1 - bf2f(h1));
  size_t o = (size_t)node * DIM + slice * 32 + lane * 2;
  *(unsigned*)(aggH + o) = (unsigned)h0 | ((unsigned)h1 << 16);
  *(unsigned*)(aggL + o) = (unsigned)l0 | ((unsigned)l1 << 16);
}

// ---------------- MFMA SAGE layer ----------------
// out = relu( (aggH+aggL)@(WlH+WlL) + xH@(WrH+WrL) + b ) via 5 bf16 segments:
//   aggH@WlH + aggL@WlH + aggH@WlL + xH@WrH + xH@WrL
__global__ __launch_bounds__(256) void sage_mfma_kernel(
    const ushort* __restrict__ aggH, const ushort* __restrict__ aggL,
    const ushort* xH,
    const ushort* __restrict__ WlH, const ushort* __restrict__ WlL,
    const ushort* __restrict__ WrH, const ushort* __restrict__ WrL,
    const float* __restrict__ bias,
    ushort* outH, int N) {
  __shared__ ushort As[128 * 64];
  __shared__ ushort Bs[128 * 64];

  const int tid = threadIdx.x;
  const int bm = blockIdx.x * 128;
  const int wave = tid >> 6;
  const int lane = tid & 63;
  const int l15 = lane & 15;
  const int quad = lane >> 4;
  const int wm = wave >> 1;
  const int wn = wave & 1;

  f32x4 acc[4][4];
#pragma unroll
  for (int i = 0; i < 4; ++i)
#pragma unroll
    for (int j = 0; j < 4; ++j) acc[i][j] = (f32x4){0.f, 0.f, 0.f, 0.f};

  for (int it = 0; it < 10; ++it) {
    const int seg = it >> 1;
    const int kt = (it & 1) << 6;
    const ushort *Ap, *Wp;
    if (seg == 0)      { Ap = aggH; Wp = WlH; }
    else if (seg == 1) { Ap = aggL; Wp = WlH; }
    else if (seg == 2) { Ap = aggH; Wp = WlL; }
    else if (seg == 3) { Ap = xH;   Wp = WrH; }
    else               { Ap = xH;   Wp = WrL; }
    __syncthreads();
#pragma unroll
    for (int c = 0; c < 4; ++c) {
      int flat = c * 256 + tid;
      int row = flat >> 3;
      int kg = flat & 7;
      int swz = (kg ^ (row & 7)) << 3;
      int grow = bm + row;
      if (grow >= N) grow = N - 1;
      *(int4*)(&As[row * 64 + swz]) = *(const int4*)(Ap + (size_t)grow * DIM + kt + kg * 8);
      *(int4*)(&Bs[row * 64 + swz]) = *(const int4*)(Wp + (size_t)row * DIM + kt + kg * 8);
    }
    __syncthreads();
#pragma unroll
    for (int ks = 0; ks < 2; ++ks) {
      bf16x8 af[4], bfr[4];
      int kg = (ks << 2) + quad;
#pragma unroll
      for (int i = 0; i < 4; ++i) {
        int ar = (wm << 6) + (i << 4) + l15;
        af[i] = *(const bf16x8*)(&As[ar * 64 + ((kg ^ (ar & 7)) << 3)]);
        int br = (wn << 6) + (i << 4) + l15;
        bfr[i] = *(const bf16x8*)(&Bs[br * 64 + ((kg ^ (br & 7)) << 3)]);
      }
#pragma unroll
      for (int i = 0; i < 4; ++i)
#pragma unroll
        for (int j = 0; j < 4; ++j)
          acc[i][j] = __builtin_amdgcn_mfma_f32_16x16x32_bf16(af[i], bfr[j], acc[i][j], 0, 0, 0);
    }
  }

  float bv[4];
#pragma unroll
  for (int j = 0; j < 4; ++j) bv[j] = bias[(wn << 6) + (j << 4) + l15];
#pragma unroll
  for (int i = 0; i < 4; ++i) {
#pragma unroll
    for (int r = 0; r < 4; ++r) {
      int grow = bm + (wm << 6) + (i << 4) + (quad << 2) + r;
      if (grow < N) {
#pragma unroll
        for (int j = 0; j < 4; ++j) {
          float v = fmaxf(acc[i][j][r] + bv[j], 0.f);
          outH[(size_t)grow * DIM + (wn << 6) + (j << 4) + l15] = f2bf(v);
        }
      }
    }
  }
}

// ---------------- layer 3 small GEMM from bf16 h ----------------
__global__ __launch_bounds__(256) void lin3_kernel(const ushort* __restrict__ hH,
                                                   const float* __restrict__ W3l,
                                                   const float* __restrict__ W3r,
                                                   float* __restrict__ y, int N) {
  __shared__ float Wc[DIM][4];
  int tid = threadIdx.x;
  if (tid < DIM) {
    Wc[tid][0] = W3l[tid * 2 + 0];
    Wc[tid][1] = W3l[tid * 2 + 1];
    Wc[tid][2] = W3r[tid * 2 + 0];
    Wc[tid][3] = W3r[tid * 2 + 1];
  }
  __syncthreads();
  int gid = blockIdx.x * 256 + tid;
  int n = gid >> 2, j = gid & 3;
  if (n >= N) return;
  const ushort* rH = hH + (size_t)n * DIM;
  float s = 0.f;
#pragma unroll 4
  for (int k8 = 0; k8 < 16; ++k8) {
    int4 a = *(const int4*)(rH + k8 * 8);
    unsigned aa[4] = {(unsigned)a.x, (unsigned)a.y, (unsigned)a.z, (unsigned)a.w};
#pragma unroll
    for (int t = 0; t < 4; ++t) {
      s += __uint_as_float(aa[t] << 16) * Wc[k8 * 8 + t * 2][j] +
           __uint_as_float(aa[t] & 0xFFFF0000u) * Wc[k8 * 8 + t * 2 + 1][j];
    }
  }
  y[gid] = s;
}

// ---------------- layer 3: 2-dim CSR gather + bias + relu + log_softmax ----------------
__global__ __launch_bounds__(256) void final3_kernel(const float* __restrict__ y,
                                                     const int* __restrict__ csr_src,
                                                     const unsigned* __restrict__ off,
                                                     const float* __restrict__ dinv,
                                                     const float* __restrict__ b3,
                                                     float* __restrict__ out, int N) {
  int n = blockIdx.x * 256 + threadIdx.x;
  if (n >= N) return;
  unsigned beg = off[n], end = off[n + 1];
  float s0 = 0.f, s1 = 0.f;
  for (unsigned e = beg; e < end; ++e) {
    int s = csr_src[e];
    float2 v = *reinterpret_cast<const float2*>(&y[(size_t)s * 4]);
    s0 += v.x; s1 += v.y;
  }
  float di = dinv[n];
  float o0 = fmaxf(s0 * di + y[(size_t)n * 4 + 2] + b3[0], 0.f);
  float o1 = fmaxf(s1 * di + y[(size_t)n * 4 + 3] + b3[1], 0.f);
  float m = fmaxf(o0, o1);
  float l = m + logf(expf(o0 - m) + expf(o1 - m));
  out[n * 2 + 0] = o0 - l;
  out[n * 2 + 1] = o1 - l;
}

extern "C" void kernel_launch(void* const* d_in, const int* in_sizes, int n_in,
                              void* d_out, int out_size, void* d_ws, size_t ws_size,
                              hipStream_t stream) {
  const float* x   = (const float*)d_in[0];
  const int*   ei  = (const int*)d_in[1];
  const float* W1l = (const float*)d_in[2];
  const float* W1r = (const float*)d_in[3];
  const float* b1  = (const float*)d_in[4];
  const float* W2l = (const float*)d_in[5];
  const float* W2r = (const float*)d_in[6];
  const float* b2  = (const float*)d_in[7];
  const float* W3l = (const float*)d_in[8];
  const float* W3r = (const float*)d_in[9];
  const float* b3  = (const float*)d_in[10];

  const int N = in_sizes[0] / DIM;  // 100000
  const int E = in_sizes[1] / 2;    // 1600000
  const int* src = ei;
  const int* dst = ei + E;
  const int B = (N + 255) / 256;

  char* ws = (char*)d_ws;
  size_t off_b = 0;
  auto alloc = [&](size_t bytes) {
    void* p = ws + off_b;
    off_b = (off_b + bytes + 255) & ~(size_t)255;
    return p;
  };
  unsigned* deg     = (unsigned*)alloc((size_t)N * 4);
  unsigned* excl    = (unsigned*)alloc((size_t)N * 4);
  unsigned* partial = (unsigned*)alloc((size_t)B * 4);
  unsigned* offs    = (unsigned*)alloc((size_t)(N + 1) * 4);
  unsigned* rank    = (unsigned*)alloc((size_t)E * 4);
  int*      csr_src = (int*)alloc((size_t)E * 4);
  float*    dinv    = (float*)alloc((size_t)N * 4);
  ushort*   xH      = (ushort*)alloc((size_t)N * DIM * 2);
  ushort*   aggH    = (ushort*)alloc((size_t)N * DIM * 2);
  ushort*   aggL    = (ushort*)alloc((size_t)N * DIM * 2);
  ushort*   wtabs   = (ushort*)alloc((size_t)8 * 16384 * 2);
  float*    y       = (float*)aggH;  // alias: agg tables dead before lin3

  // ---- CSR build ----
  hipMemsetAsync(deg, 0, (size_t)N * 4, stream);
  hist_rank_kernel<<<(E + 255) / 256, 256, 0, stream>>>(dst, deg, rank, E);
  scan_block_kernel<<<B, 256, 0, stream>>>(deg, excl, partial, dinv, N);
  scan_partials_kernel<<<1, 256, 0, stream>>>(partial, B);
  add_offsets_kernel<<<(N + 256) / 256, 256, 0, stream>>>(excl, partial, offs, N, E);
  csr_fill_kernel<<<(E + 255) / 256, 256, 0, stream>>>(src, dst, rank, offs, csr_src, E);

  // ---- precision prep ----
  cast_kernel<<<(int)(((size_t)N * DIM / 4 + 255) / 256), 256, 0, stream>>>(
      x, xH, (long)N * DIM);
  wsplit_kernel<<<dim3(64, 4), 256, 0, stream>>>(W1l, W1r, W2l, W2r, wtabs);
  const ushort* W1lH = wtabs;           const ushort* W1lL = wtabs + 16384;
  const ushort* W1rH = wtabs + 32768;   const ushort* W1rL = wtabs + 49152;
  const ushort* W2lH = wtabs + 65536;   const ushort* W2lL = wtabs + 81920;
  const ushort* W2rH = wtabs + 98304;   const ushort* W2rL = wtabs + 114688;

  const int gemm_grid = (N + 127) / 128;
  const int gather_grid = ((N + 15) / 16) * 4;

  // ---- layer 1 (h1 written in-place over xH) ----
  gather_slice_kernel<<<gather_grid, 256, 0, stream>>>(xH, csr_src, offs, dinv, aggH, aggL, N);
  sage_mfma_kernel<<<gemm_grid, 256, 0, stream>>>(aggH, aggL, xH, W1lH, W1lL, W1rH, W1rL,
                                                  b1, xH, N);
  // ---- layer 2 (in-place again) ----
  gather_slice_kernel<<<gather_grid, 256, 0, stream>>>(xH, csr_src, offs, dinv, aggH, aggL, N);
  sage_mfma_kernel<<<gemm_grid, 256, 0, stream>>>(aggH, aggL, xH, W2lH, W2lL, W2rH, W2rL,
                                                  b2, xH, N);
  // ---- layer 3 ----
  lin3_kernel<<<(N * 4 + 255) / 256, 256, 0, stream>>>(xH, W3l, W3r, y, N);
  final3_kernel<<<(N + 255) / 256, 256, 0, stream>>>(y, csr_src, offs, dinv, b3, (float*)d_out, N);
}

// Round 6
// 432.275 us; speedup vs baseline: 1.3831x; 1.3831x over previous
//
#include <hip/hip_runtime.h>
#include <hip/hip_bf16.h>
#include <math.h>

#define DIM 128

typedef __attribute__((ext_vector_type(8))) short bf16x8;
typedef __attribute__((ext_vector_type(4))) float f32x4;

__device__ __forceinline__ ushort f2bf(float f) {  // RTNE
  unsigned u = __float_as_uint(f);
  return (ushort)((u + 0x7FFFu + ((u >> 16) & 1u)) >> 16);
}
__device__ __forceinline__ float bf2f(ushort h) {
  return __uint_as_float(((unsigned)h) << 16);
}

// ---------------- degree histogram + per-edge rank ----------------
__global__ __launch_bounds__(256) void hist_rank_kernel(const int* __restrict__ dst,
                                                        unsigned* __restrict__ deg,
                                                        unsigned* __restrict__ rank, int E) {
  int gid = blockIdx.x * 256 + threadIdx.x;
  if (gid < E) rank[gid] = atomicAdd(&deg[dst[gid]], 1u);
}

// ---------------- two-level exclusive scan over deg (+ fused dinv) ----------------
__global__ __launch_bounds__(256) void scan_block_kernel(const unsigned* __restrict__ deg,
                                                         unsigned* __restrict__ excl,
                                                         unsigned* __restrict__ partial,
                                                         float* __restrict__ dinv, int N) {
  __shared__ unsigned s[256];
  int i = blockIdx.x * 256 + threadIdx.x;
  unsigned v = (i < N) ? deg[i] : 0u;
  if (i < N) dinv[i] = 1.0f / fmaxf((float)v, 1.0f);
  s[threadIdx.x] = v;
  __syncthreads();
#pragma unroll
  for (int d = 1; d < 256; d <<= 1) {
    unsigned t = (threadIdx.x >= d) ? s[threadIdx.x - d] : 0u;
    __syncthreads();
    s[threadIdx.x] += t;
    __syncthreads();
  }
  if (i < N) excl[i] = s[threadIdx.x] - v;
  if (threadIdx.x == 255) partial[blockIdx.x] = s[255];
}

__global__ __launch_bounds__(256) void scan_partials_kernel(unsigned* __restrict__ partial, int B) {
  __shared__ unsigned s[256];
  __shared__ unsigned carry;
  if (threadIdx.x == 0) carry = 0u;
  __syncthreads();
  for (int base = 0; base < B; base += 256) {
    int i = base + threadIdx.x;
    unsigned v = (i < B) ? partial[i] : 0u;
    s[threadIdx.x] = v;
    __syncthreads();
#pragma unroll
    for (int d = 1; d < 256; d <<= 1) {
      unsigned t = (threadIdx.x >= d) ? s[threadIdx.x - d] : 0u;
      __syncthreads();
      s[threadIdx.x] += t;
      __syncthreads();
    }
    if (i < B) partial[i] = carry + s[threadIdx.x] - v;
    __syncthreads();
    if (threadIdx.x == 0) carry += s[255];
    __syncthreads();
  }
}

__global__ __launch_bounds__(256) void add_offsets_kernel(const unsigned* __restrict__ excl,
                                                          const unsigned* __restrict__ partial,
                                                          unsigned* __restrict__ off, int N, int E) {
  int i = blockIdx.x * 256 + threadIdx.x;
  if (i < N) off[i] = excl[i] + partial[i >> 8];
  if (i == N) off[N] = (unsigned)E;
}

// ---------------- CSR fill: atomic-free ----------------
__global__ __launch_bounds__(256) void csr_fill_kernel(const int* __restrict__ src,
                                                       const int* __restrict__ dst,
                                                       const unsigned* __restrict__ rank,
                                                       const unsigned* __restrict__ off,
                                                       int* __restrict__ csr_src, int E) {
  int e = blockIdx.x * 256 + threadIdx.x;
  if (e >= E) return;
  csr_src[off[dst[e]] + rank[e]] = src[e];
}

// ---------------- fp32 -> bf16 cast ----------------
__global__ __launch_bounds__(256) void cast_kernel(const float* __restrict__ x,
                                                   ushort* __restrict__ xh, long total) {
  long i = ((long)blockIdx.x * 256 + threadIdx.x) * 4;
  if (i >= total) return;
  float4 v = *(const float4*)(x + i);
  uint2 H;
  H.x = (unsigned)f2bf(v.x) | ((unsigned)f2bf(v.y) << 16);
  H.y = (unsigned)f2bf(v.z) | ((unsigned)f2bf(v.w) << 16);
  *(uint2*)(xh + i) = H;
}

// ---------------- W fp32 [k][n] -> transposed bf16 hi/lo tables [n][k] ----------------
__global__ __launch_bounds__(256) void wsplit_kernel(const float* __restrict__ W1l,
                                                     const float* __restrict__ W1r,
                                                     const float* __restrict__ W2l,
                                                     const float* __restrict__ W2r,
                                                     ushort* __restrict__ tabs) {
  int m = blockIdx.y;
  const float* W = (m == 0) ? W1l : (m == 1) ? W1r : (m == 2) ? W2l : W2r;
  ushort* H = tabs + (size_t)m * 32768;
  ushort* L = H + 16384;
  int idx = blockIdx.x * 256 + threadIdx.x;  // 0..16383
  int k = idx >> 7, n = idx & 127;
  float v = W[idx];
  ushort h = f2bf(v);
  H[n * DIM + k] = h;
  L[n * DIM + k] = f2bf(v - bf2f(h));
}

// ---------------- wave-per-node gather-aggregate ----------------
// 64 lanes = 4 edge-slots x 16 cols x 16 B (full 256 B rows: no line over-fetch).
// Unroll x2 -> 8 independent feature-row loads in flight per wave; no cross-node
// divergence (wave runtime = ceil(deg/4), not max-degree-of-peers).
__global__ __launch_bounds__(256) void gather_wave_kernel(
    const ushort* __restrict__ featH, const int* __restrict__ csr_src,
    const unsigned* __restrict__ off, const float* __restrict__ dinv,
    ushort* __restrict__ aggH, ushort* __restrict__ aggL, int N) {
  const int node = (blockIdx.x * 256 + threadIdx.x) >> 6;  // one wave per node
  if (node >= N) return;
  const int lane = threadIdx.x & 63;
  const int eslot = lane >> 4;   // 0..3
  const int col = lane & 15;     // 16 B slice of the 256 B row
  const unsigned beg = off[node], end = off[node + 1];
  const ushort* fbase = featH + col * 8;

  float acc[8];
#pragma unroll
  for (int t = 0; t < 8; ++t) acc[t] = 0.f;

  auto accum = [&](int4 v) {
    unsigned w0 = (unsigned)v.x, w1 = (unsigned)v.y, w2 = (unsigned)v.z, w3 = (unsigned)v.w;
    acc[0] += __uint_as_float(w0 << 16);
    acc[1] += __uint_as_float(w0 & 0xFFFF0000u);
    acc[2] += __uint_as_float(w1 << 16);
    acc[3] += __uint_as_float(w1 & 0xFFFF0000u);
    acc[4] += __uint_as_float(w2 << 16);
    acc[5] += __uint_as_float(w2 & 0xFFFF0000u);
    acc[6] += __uint_as_float(w3 << 16);
    acc[7] += __uint_as_float(w3 & 0xFFFF0000u);
  };

  unsigned base = beg;
  for (; base + 8 <= end; base += 8) {
    int s0 = csr_src[base + eslot];
    int s1 = csr_src[base + 4 + eslot];
    int4 v0 = *(const int4*)(fbase + (size_t)s0 * DIM);
    int4 v1 = *(const int4*)(fbase + (size_t)s1 * DIM);
    accum(v0);
    accum(v1);
  }
  for (unsigned e = base + eslot; e < end; e += 4) {
    int s = csr_src[e];
    int4 v = *(const int4*)(fbase + (size_t)s * DIM);
    accum(v);
  }

  // reduce the 4 edge-slot partials (lanes differing in bits 5,4)
#pragma unroll
  for (int t = 0; t < 8; ++t) {
    acc[t] += __shfl_xor(acc[t], 32, 64);
    acc[t] += __shfl_xor(acc[t], 16, 64);
  }

  if (eslot == 0) {
    float di = dinv[node];
    unsigned ph[4], pl[4];
#pragma unroll
    for (int t = 0; t < 4; ++t) {
      float f0 = acc[2 * t] * di, f1 = acc[2 * t + 1] * di;
      ushort h0 = f2bf(f0), h1 = f2bf(f1);
      ushort l0 = f2bf(f0 - bf2f(h0)), l1 = f2bf(f1 - bf2f(h1));
      ph[t] = (unsigned)h0 | ((unsigned)h1 << 16);
      pl[t] = (unsigned)l0 | ((unsigned)l1 << 16);
    }
    size_t o = (size_t)node * DIM + col * 8;
    *(int4*)(aggH + o) = make_int4((int)ph[0], (int)ph[1], (int)ph[2], (int)ph[3]);
    *(int4*)(aggL + o) = make_int4((int)pl[0], (int)pl[1], (int)pl[2], (int)pl[3]);
  }
}

// ---------------- MFMA SAGE layer ----------------
// out = relu( (aggH+aggL)@(WlH+WlL) + xH@(WrH+WrL) + b ) via 5 bf16 segments:
//   aggH@WlH + aggL@WlH + aggH@WlL + xH@WrH + xH@WrL
__global__ __launch_bounds__(256) void sage_mfma_kernel(
    const ushort* __restrict__ aggH, const ushort* __restrict__ aggL,
    const ushort* xH,
    const ushort* __restrict__ WlH, const ushort* __restrict__ WlL,
    const ushort* __restrict__ WrH, const ushort* __restrict__ WrL,
    const float* __restrict__ bias,
    ushort* outH, int N) {
  __shared__ ushort As[128 * 64];
  __shared__ ushort Bs[128 * 64];

  const int tid = threadIdx.x;
  const int bm = blockIdx.x * 128;
  const int wave = tid >> 6;
  const int lane = tid & 63;
  const int l15 = lane & 15;
  const int quad = lane >> 4;
  const int wm = wave >> 1;
  const int wn = wave & 1;

  f32x4 acc[4][4];
#pragma unroll
  for (int i = 0; i < 4; ++i)
#pragma unroll
    for (int j = 0; j < 4; ++j) acc[i][j] = (f32x4){0.f, 0.f, 0.f, 0.f};

  for (int it = 0; it < 10; ++it) {
    const int seg = it >> 1;
    const int kt = (it & 1) << 6;
    const ushort *Ap, *Wp;
    if (seg == 0)      { Ap = aggH; Wp = WlH; }
    else if (seg == 1) { Ap = aggL; Wp = WlH; }
    else if (seg == 2) { Ap = aggH; Wp = WlL; }
    else if (seg == 3) { Ap = xH;   Wp = WrH; }
    else               { Ap = xH;   Wp = WrL; }
    __syncthreads();
#pragma unroll
    for (int c = 0; c < 4; ++c) {
      int flat = c * 256 + tid;
      int row = flat >> 3;
      int kg = flat & 7;
      int swz = (kg ^ (row & 7)) << 3;
      int grow = bm + row;
      if (grow >= N) grow = N - 1;
      *(int4*)(&As[row * 64 + swz]) = *(const int4*)(Ap + (size_t)grow * DIM + kt + kg * 8);
      *(int4*)(&Bs[row * 64 + swz]) = *(const int4*)(Wp + (size_t)row * DIM + kt + kg * 8);
    }
    __syncthreads();
#pragma unroll
    for (int ks = 0; ks < 2; ++ks) {
      bf16x8 af[4], bfr[4];
      int kg = (ks << 2) + quad;
#pragma unroll
      for (int i = 0; i < 4; ++i) {
        int ar = (wm << 6) + (i << 4) + l15;
        af[i] = *(const bf16x8*)(&As[ar * 64 + ((kg ^ (ar & 7)) << 3)]);
        int br = (wn << 6) + (i << 4) + l15;
        bfr[i] = *(const bf16x8*)(&Bs[br * 64 + ((kg ^ (br & 7)) << 3)]);
      }
#pragma unroll
      for (int i = 0; i < 4; ++i)
#pragma unroll
        for (int j = 0; j < 4; ++j)
          acc[i][j] = __builtin_amdgcn_mfma_f32_16x16x32_bf16(af[i], bfr[j], acc[i][j], 0, 0, 0);
    }
  }

  float bv[4];
#pragma unroll
  for (int j = 0; j < 4; ++j) bv[j] = bias[(wn << 6) + (j << 4) + l15];
#pragma unroll
  for (int i = 0; i < 4; ++i) {
#pragma unroll
    for (int r = 0; r < 4; ++r) {
      int grow = bm + (wm << 6) + (i << 4) + (quad << 2) + r;
      if (grow < N) {
#pragma unroll
        for (int j = 0; j < 4; ++j) {
          float v = fmaxf(acc[i][j][r] + bv[j], 0.f);
          outH[(size_t)grow * DIM + (wn << 6) + (j << 4) + l15] = f2bf(v);
        }
      }
    }
  }
}

// ---------------- layer 3 small GEMM from bf16 h ----------------
__global__ __launch_bounds__(256) void lin3_kernel(const ushort* __restrict__ hH,
                                                   const float* __restrict__ W3l,
                                                   const float* __restrict__ W3r,
                                                   float* __restrict__ y, int N) {
  __shared__ float Wc[DIM][4];
  int tid = threadIdx.x;
  if (tid < DIM) {
    Wc[tid][0] = W3l[tid * 2 + 0];
    Wc[tid][1] = W3l[tid * 2 + 1];
    Wc[tid][2] = W3r[tid * 2 + 0];
    Wc[tid][3] = W3r[tid * 2 + 1];
  }
  __syncthreads();
  int gid = blockIdx.x * 256 + tid;
  int n = gid >> 2, j = gid & 3;
  if (n >= N) return;
  const ushort* rH = hH + (size_t)n * DIM;
  float s = 0.f;
#pragma unroll 4
  for (int k8 = 0; k8 < 16; ++k8) {
    int4 a = *(const int4*)(rH + k8 * 8);
    unsigned aa[4] = {(unsigned)a.x, (unsigned)a.y, (unsigned)a.z, (unsigned)a.w};
#pragma unroll
    for (int t = 0; t < 4; ++t) {
      s += __uint_as_float(aa[t] << 16) * Wc[k8 * 8 + t * 2][j] +
           __uint_as_float(aa[t] & 0xFFFF0000u) * Wc[k8 * 8 + t * 2 + 1][j];
    }
  }
  y[gid] = s;
}

// ---------------- layer 3: 2-dim CSR gather + bias + relu + log_softmax ----------------
__global__ __launch_bounds__(256) void final3_kernel(const float* __restrict__ y,
                                                     const int* __restrict__ csr_src,
                                                     const unsigned* __restrict__ off,
                                                     const float* __restrict__ dinv,
                                                     const float* __restrict__ b3,
                                                     float* __restrict__ out, int N) {
  int n = blockIdx.x * 256 + threadIdx.x;
  if (n >= N) return;
  unsigned beg = off[n], end = off[n + 1];
  float s0 = 0.f, s1 = 0.f;
  for (unsigned e = beg; e < end; ++e) {
    int s = csr_src[e];
    float2 v = *reinterpret_cast<const float2*>(&y[(size_t)s * 4]);
    s0 += v.x; s1 += v.y;
  }
  float di = dinv[n];
  float o0 = fmaxf(s0 * di + y[(size_t)n * 4 + 2] + b3[0], 0.f);
  float o1 = fmaxf(s1 * di + y[(size_t)n * 4 + 3] + b3[1], 0.f);
  float m = fmaxf(o0, o1);
  float l = m + logf(expf(o0 - m) + expf(o1 - m));
  out[n * 2 + 0] = o0 - l;
  out[n * 2 + 1] = o1 - l;
}

extern "C" void kernel_launch(void* const* d_in, const int* in_sizes, int n_in,
                              void* d_out, int out_size, void* d_ws, size_t ws_size,
                              hipStream_t stream) {
  const float* x   = (const float*)d_in[0];
  const int*   ei  = (const int*)d_in[1];
  const float* W1l = (const float*)d_in[2];
  const float* W1r = (const float*)d_in[3];
  const float* b1  = (const float*)d_in[4];
  const float* W2l = (const float*)d_in[5];
  const float* W2r = (const float*)d_in[6];
  const float* b2  = (const float*)d_in[7];
  const float* W3l = (const float*)d_in[8];
  const float* W3r = (const float*)d_in[9];
  const float* b3  = (const float*)d_in[10];

  const int N = in_sizes[0] / DIM;  // 100000
  const int E = in_sizes[1] / 2;    // 1600000
  const int* src = ei;
  const int* dst = ei + E;
  const int B = (N + 255) / 256;

  char* ws = (char*)d_ws;
  size_t off_b = 0;
  auto alloc = [&](size_t bytes) {
    void* p = ws + off_b;
    off_b = (off_b + bytes + 255) & ~(size_t)255;
    return p;
  };
  unsigned* deg     = (unsigned*)alloc((size_t)N * 4);
  unsigned* excl    = (unsigned*)alloc((size_t)N * 4);
  unsigned* partial = (unsigned*)alloc((size_t)B * 4);
  unsigned* offs    = (unsigned*)alloc((size_t)(N + 1) * 4);
  unsigned* rank    = (unsigned*)alloc((size_t)E * 4);
  int*      csr_src = (int*)alloc((size_t)E * 4);
  float*    dinv    = (float*)alloc((size_t)N * 4);
  ushort*   xH      = (ushort*)alloc((size_t)N * DIM * 2);
  ushort*   aggH    = (ushort*)alloc((size_t)N * DIM * 2);
  ushort*   aggL    = (ushort*)alloc((size_t)N * DIM * 2);
  ushort*   wtabs   = (ushort*)alloc((size_t)8 * 16384 * 2);
  float*    y       = (float*)aggH;  // alias: agg tables dead before lin3

  // ---- CSR build ----
  hipMemsetAsync(deg, 0, (size_t)N * 4, stream);
  hist_rank_kernel<<<(E + 255) / 256, 256, 0, stream>>>(dst, deg, rank, E);
  scan_block_kernel<<<B, 256, 0, stream>>>(deg, excl, partial, dinv, N);
  scan_partials_kernel<<<1, 256, 0, stream>>>(partial, B);
  add_offsets_kernel<<<(N + 256) / 256, 256, 0, stream>>>(excl, partial, offs, N, E);
  csr_fill_kernel<<<(E + 255) / 256, 256, 0, stream>>>(src, dst, rank, offs, csr_src, E);

  // ---- precision prep ----
  cast_kernel<<<(int)(((size_t)N * DIM / 4 + 255) / 256), 256, 0, stream>>>(
      x, xH, (long)N * DIM);
  wsplit_kernel<<<dim3(64, 4), 256, 0, stream>>>(W1l, W1r, W2l, W2r, wtabs);
  const ushort* W1lH = wtabs;           const ushort* W1lL = wtabs + 16384;
  const ushort* W1rH = wtabs + 32768;   const ushort* W1rL = wtabs + 49152;
  const ushort* W2lH = wtabs + 65536;   const ushort* W2lL = wtabs + 81920;
  const ushort* W2rH = wtabs + 98304;   const ushort* W2rL = wtabs + 114688;

  const int gemm_grid = (N + 127) / 128;
  const int gather_grid = (N + 3) / 4;  // one wave (64 lanes) per node

  // ---- layer 1 (h1 written in-place over xH) ----
  gather_wave_kernel<<<gather_grid, 256, 0, stream>>>(xH, csr_src, offs, dinv, aggH, aggL, N);
  sage_mfma_kernel<<<gemm_grid, 256, 0, stream>>>(aggH, aggL, xH, W1lH, W1lL, W1rH, W1rL,
                                                  b1, xH, N);
  // ---- layer 2 (in-place again) ----
  gather_wave_kernel<<<gather_grid, 256, 0, stream>>>(xH, csr_src, offs, dinv, aggH, aggL, N);
  sage_mfma_kernel<<<gemm_grid, 256, 0, stream>>>(aggH, aggL, xH, W2lH, W2lL, W2rH, W2rL,
                                                  b2, xH, N);
  // ---- layer 3 ----
  lin3_kernel<<<(N * 4 + 255) / 256, 256, 0, stream>>>(xH, W3l, W3r, y, N);
  final3_kernel<<<(N + 255) / 256, 256, 0, stream>>>(y, csr_src, offs, dinv, b3, (float*)d_out, N);
}

// Round 7
// 422.859 us; speedup vs baseline: 1.4139x; 1.0223x over previous
//
#include <hip/hip_runtime.h>
#include <hip/hip_bf16.h>
#include <math.h>

#define DIM 128

typedef __attribute__((ext_vector_type(8))) short bf16x8;
typedef __attribute__((ext_vector_type(4))) float f32x4;

__device__ __forceinline__ ushort f2bf(float f) {  // RTNE
  unsigned u = __float_as_uint(f);
  return (ushort)((u + 0x7FFFu + ((u >> 16) & 1u)) >> 16);
}
__device__ __forceinline__ float bf2f(ushort h) {
  return __uint_as_float(((unsigned)h) << 16);
}

// ---------------- fused prep: hist_rank || cast || wsplit ----------------
// blocks [0,H): histogram+rank; [H,H+C): fp32->bf16 cast of x; [H+C,H+C+256): wsplit.
// hist blocks first so the atomic-bound work starts immediately; cast/wsplit hide under it.
__global__ __launch_bounds__(256) void prep_kernel(
    const int* __restrict__ dst, unsigned* __restrict__ deg, unsigned* __restrict__ rank, int E,
    const float* __restrict__ x, ushort* __restrict__ xh, long total,
    const float* __restrict__ W1l, const float* __restrict__ W1r,
    const float* __restrict__ W2l, const float* __restrict__ W2r,
    ushort* __restrict__ tabs, int H, int C) {
  int bid = blockIdx.x;
  if (bid < H) {
    int gid = bid * 256 + threadIdx.x;
    if (gid < E) rank[gid] = atomicAdd(&deg[dst[gid]], 1u);
    return;
  }
  bid -= H;
  if (bid < C) {
    long i = ((long)bid * 256 + threadIdx.x) * 4;
    if (i >= total) return;
    float4 v = *(const float4*)(x + i);
    uint2 Hh;
    Hh.x = (unsigned)f2bf(v.x) | ((unsigned)f2bf(v.y) << 16);
    Hh.y = (unsigned)f2bf(v.z) | ((unsigned)f2bf(v.w) << 16);
    *(uint2*)(xh + i) = Hh;
    return;
  }
  bid -= C;  // 0..255 : wsplit, m = bid>>6, 64 blocks per matrix
  int m = bid >> 6;
  const float* W = (m == 0) ? W1l : (m == 1) ? W1r : (m == 2) ? W2l : W2r;
  ushort* Ht = tabs + (size_t)m * 32768;
  ushort* Lt = Ht + 16384;
  int idx = (bid & 63) * 256 + threadIdx.x;  // 0..16383
  int k = idx >> 7, n = idx & 127;
  float v = W[idx];
  ushort h = f2bf(v);
  Ht[n * DIM + k] = h;
  Lt[n * DIM + k] = f2bf(v - bf2f(h));
}

// ---------------- two-level exclusive scan over deg (+ fused dinv) ----------------
__global__ __launch_bounds__(256) void scan_block_kernel(const unsigned* __restrict__ deg,
                                                         unsigned* __restrict__ excl,
                                                         unsigned* __restrict__ partial,
                                                         float* __restrict__ dinv, int N) {
  __shared__ unsigned s[256];
  int i = blockIdx.x * 256 + threadIdx.x;
  unsigned v = (i < N) ? deg[i] : 0u;
  if (i < N) dinv[i] = 1.0f / fmaxf((float)v, 1.0f);
  s[threadIdx.x] = v;
  __syncthreads();
#pragma unroll
  for (int d = 1; d < 256; d <<= 1) {
    unsigned t = (threadIdx.x >= d) ? s[threadIdx.x - d] : 0u;
    __syncthreads();
    s[threadIdx.x] += t;
    __syncthreads();
  }
  if (i < N) excl[i] = s[threadIdx.x] - v;
  if (threadIdx.x == 255) partial[blockIdx.x] = s[255];
}

__global__ __launch_bounds__(256) void scan_partials_kernel(unsigned* __restrict__ partial, int B) {
  __shared__ unsigned s[256];
  __shared__ unsigned carry;
  if (threadIdx.x == 0) carry = 0u;
  __syncthreads();
  for (int base = 0; base < B; base += 256) {
    int i = base + threadIdx.x;
    unsigned v = (i < B) ? partial[i] : 0u;
    s[threadIdx.x] = v;
    __syncthreads();
#pragma unroll
    for (int d = 1; d < 256; d <<= 1) {
      unsigned t = (threadIdx.x >= d) ? s[threadIdx.x - d] : 0u;
      __syncthreads();
      s[threadIdx.x] += t;
      __syncthreads();
    }
    if (i < B) partial[i] = carry + s[threadIdx.x] - v;
    __syncthreads();
    if (threadIdx.x == 0) carry += s[255];
    __syncthreads();
  }
}

__global__ __launch_bounds__(256) void add_offsets_kernel(const unsigned* __restrict__ excl,
                                                          const unsigned* __restrict__ partial,
                                                          unsigned* __restrict__ off, int N, int E) {
  int i = blockIdx.x * 256 + threadIdx.x;
  if (i < N) off[i] = excl[i] + partial[i >> 8];
  if (i == N) off[N] = (unsigned)E;
}

// ---------------- CSR fill: atomic-free ----------------
__global__ __launch_bounds__(256) void csr_fill_kernel(const int* __restrict__ src,
                                                       const int* __restrict__ dst,
                                                       const unsigned* __restrict__ rank,
                                                       const unsigned* __restrict__ off,
                                                       int* __restrict__ csr_src, int E) {
  int e = blockIdx.x * 256 + threadIdx.x;
  if (e >= E) return;
  csr_src[off[dst[e]] + rank[e]] = src[e];
}

// ---------------- wave-per-node gather-aggregate (hi only) ----------------
// 64 lanes = 4 edge-slots x 16 cols x 16 B; unroll x2 -> 8 loads in flight/wave.
__global__ __launch_bounds__(256) void gather_wave_kernel(
    const ushort* __restrict__ featH, const int* __restrict__ csr_src,
    const unsigned* __restrict__ off, const float* __restrict__ dinv,
    ushort* __restrict__ aggH, int N) {
  const int node = (blockIdx.x * 256 + threadIdx.x) >> 6;
  if (node >= N) return;
  const int lane = threadIdx.x & 63;
  const int eslot = lane >> 4;
  const int col = lane & 15;
  const unsigned beg = off[node], end = off[node + 1];
  const ushort* fbase = featH + col * 8;

  float acc[8];
#pragma unroll
  for (int t = 0; t < 8; ++t) acc[t] = 0.f;

  auto accum = [&](int4 v) {
    unsigned w0 = (unsigned)v.x, w1 = (unsigned)v.y, w2 = (unsigned)v.z, w3 = (unsigned)v.w;
    acc[0] += __uint_as_float(w0 << 16);
    acc[1] += __uint_as_float(w0 & 0xFFFF0000u);
    acc[2] += __uint_as_float(w1 << 16);
    acc[3] += __uint_as_float(w1 & 0xFFFF0000u);
    acc[4] += __uint_as_float(w2 << 16);
    acc[5] += __uint_as_float(w2 & 0xFFFF0000u);
    acc[6] += __uint_as_float(w3 << 16);
    acc[7] += __uint_as_float(w3 & 0xFFFF0000u);
  };

  unsigned base = beg;
  for (; base + 8 <= end; base += 8) {
    int s0 = csr_src[base + eslot];
    int s1 = csr_src[base + 4 + eslot];
    int4 v0 = *(const int4*)(fbase + (size_t)s0 * DIM);
    int4 v1 = *(const int4*)(fbase + (size_t)s1 * DIM);
    accum(v0);
    accum(v1);
  }
  for (unsigned e = base + eslot; e < end; e += 4) {
    int s = csr_src[e];
    int4 v = *(const int4*)(fbase + (size_t)s * DIM);
    accum(v);
  }

#pragma unroll
  for (int t = 0; t < 8; ++t) {
    acc[t] += __shfl_xor(acc[t], 32, 64);
    acc[t] += __shfl_xor(acc[t], 16, 64);
  }

  if (eslot == 0) {
    float di = dinv[node];
    unsigned ph[4];
#pragma unroll
    for (int t = 0; t < 4; ++t) {
      ph[t] = (unsigned)f2bf(acc[2 * t] * di) | ((unsigned)f2bf(acc[2 * t + 1] * di) << 16);
    }
    *(int4*)(aggH + (size_t)node * DIM + col * 8) =
        make_int4((int)ph[0], (int)ph[1], (int)ph[2], (int)ph[3]);
  }
}

// ---------------- MFMA SAGE layer (optional fused lin3 -> y) ----------------
// out = relu( aggH@(WlH+WlL) + xH@(WrH+WrL) + b ) via 4 bf16 segments.
// If W3l != nullptr, also y[n][0..3] = bf16(out[n]) . [W3l | W3r]  (exactly what a
// separate lin3 pass reading bf16 h would compute).
__global__ __launch_bounds__(256) void sage_mfma_kernel(
    const ushort* __restrict__ aggH, const ushort* xH,
    const ushort* __restrict__ WlH, const ushort* __restrict__ WlL,
    const ushort* __restrict__ WrH, const ushort* __restrict__ WrL,
    const float* __restrict__ bias,
    const float* __restrict__ W3l, const float* __restrict__ W3r,
    ushort* outH, float* __restrict__ y, int N) {
  __shared__ ushort As[128 * 64];
  __shared__ ushort Bs[128 * 64];
  __shared__ float Wc[128][4];
  __shared__ float Yp[128][4][2];

  const int tid = threadIdx.x;
  const int bm = blockIdx.x * 128;
  const int wave = tid >> 6;
  const int lane = tid & 63;
  const int l15 = lane & 15;
  const int quad = lane >> 4;
  const int wm = wave >> 1;
  const int wn = wave & 1;

  if (W3l && tid < 128) {
    Wc[tid][0] = W3l[tid * 2 + 0];
    Wc[tid][1] = W3l[tid * 2 + 1];
    Wc[tid][2] = W3r[tid * 2 + 0];
    Wc[tid][3] = W3r[tid * 2 + 1];
  }

  f32x4 acc[4][4];
#pragma unroll
  for (int i = 0; i < 4; ++i)
#pragma unroll
    for (int j = 0; j < 4; ++j) acc[i][j] = (f32x4){0.f, 0.f, 0.f, 0.f};

  for (int it = 0; it < 8; ++it) {
    const int seg = it >> 1;
    const int kt = (it & 1) << 6;
    const ushort *Ap, *Wp;
    if (seg == 0)      { Ap = aggH; Wp = WlH; }
    else if (seg == 1) { Ap = aggH; Wp = WlL; }
    else if (seg == 2) { Ap = xH;   Wp = WrH; }
    else               { Ap = xH;   Wp = WrL; }
    __syncthreads();
#pragma unroll
    for (int c = 0; c < 4; ++c) {
      int flat = c * 256 + tid;
      int row = flat >> 3;
      int kg = flat & 7;
      int swz = (kg ^ (row & 7)) << 3;
      int grow = bm + row;
      if (grow >= N) grow = N - 1;
      *(int4*)(&As[row * 64 + swz]) = *(const int4*)(Ap + (size_t)grow * DIM + kt + kg * 8);
      *(int4*)(&Bs[row * 64 + swz]) = *(const int4*)(Wp + (size_t)row * DIM + kt + kg * 8);
    }
    __syncthreads();
#pragma unroll
    for (int ks = 0; ks < 2; ++ks) {
      bf16x8 af[4], bfr[4];
      int kg = (ks << 2) + quad;
#pragma unroll
      for (int i = 0; i < 4; ++i) {
        int ar = (wm << 6) + (i << 4) + l15;
        af[i] = *(const bf16x8*)(&As[ar * 64 + ((kg ^ (ar & 7)) << 3)]);
        int br = (wn << 6) + (i << 4) + l15;
        bfr[i] = *(const bf16x8*)(&Bs[br * 64 + ((kg ^ (br & 7)) << 3)]);
      }
#pragma unroll
      for (int i = 0; i < 4; ++i)
#pragma unroll
        for (int j = 0; j < 4; ++j)
          acc[i][j] = __builtin_amdgcn_mfma_f32_16x16x32_bf16(af[i], bfr[j], acc[i][j], 0, 0, 0);
    }
  }

  float bv[4];
#pragma unroll
  for (int j = 0; j < 4; ++j) bv[j] = bias[(wn << 6) + (j << 4) + l15];

#pragma unroll
  for (int i = 0; i < 4; ++i) {
#pragma unroll
    for (int r = 0; r < 4; ++r) {
      const int rowl = (wm << 6) + (i << 4) + (quad << 2) + r;
      const int grow = bm + rowl;
      float p0 = 0.f, p1 = 0.f, p2 = 0.f, p3 = 0.f;
#pragma unroll
      for (int j = 0; j < 4; ++j) {
        float v = fmaxf(acc[i][j][r] + bv[j], 0.f);
        ushort h = f2bf(v);
        if (grow < N) outH[(size_t)grow * DIM + (wn << 6) + (j << 4) + l15] = h;
        if (W3l) {
          float q = bf2f(h);  // match bf16-rounded h exactly
          int col = (wn << 6) + (j << 4) + l15;
          p0 += q * Wc[col][0];
          p1 += q * Wc[col][1];
          p2 += q * Wc[col][2];
          p3 += q * Wc[col][3];
        }
      }
      if (W3l) {
        // reduce over the 16 l15 lanes (xor of lane bits 0..3 stays in-group)
#pragma unroll
        for (int o = 1; o < 16; o <<= 1) {
          p0 += __shfl_xor(p0, o, 64);
          p1 += __shfl_xor(p1, o, 64);
          p2 += __shfl_xor(p2, o, 64);
          p3 += __shfl_xor(p3, o, 64);
        }
        if (l15 == 0) {
          Yp[rowl][0][wn] = p0;
          Yp[rowl][1][wn] = p1;
          Yp[rowl][2][wn] = p2;
          Yp[rowl][3][wn] = p3;
        }
      }
    }
  }

  if (W3l) {
    __syncthreads();
    for (int t = tid; t < 512; t += 256) {
      int row = t >> 2, c = t & 3;
      int grow = bm + row;
      if (grow < N) y[(size_t)grow * 4 + c] = Yp[row][c][0] + Yp[row][c][1];
    }
  }
}

// ---------------- layer 3: 2-dim CSR gather + bias + relu + log_softmax ----------------
__global__ __launch_bounds__(256) void final3_kernel(const float* __restrict__ y,
                                                     const int* __restrict__ csr_src,
                                                     const unsigned* __restrict__ off,
                                                     const float* __restrict__ dinv,
                                                     const float* __restrict__ b3,
                                                     float* __restrict__ out, int N) {
  int n = blockIdx.x * 256 + threadIdx.x;
  if (n >= N) return;
  unsigned beg = off[n], end = off[n + 1];
  float s0 = 0.f, s1 = 0.f;
  for (unsigned e = beg; e < end; ++e) {
    int s = csr_src[e];
    float2 v = *reinterpret_cast<const float2*>(&y[(size_t)s * 4]);
    s0 += v.x; s1 += v.y;
  }
  float di = dinv[n];
  float o0 = fmaxf(s0 * di + y[(size_t)n * 4 + 2] + b3[0], 0.f);
  float o1 = fmaxf(s1 * di + y[(size_t)n * 4 + 3] + b3[1], 0.f);
  float m = fmaxf(o0, o1);
  float l = m + logf(expf(o0 - m) + expf(o1 - m));
  out[n * 2 + 0] = o0 - l;
  out[n * 2 + 1] = o1 - l;
}

extern "C" void kernel_launch(void* const* d_in, const int* in_sizes, int n_in,
                              void* d_out, int out_size, void* d_ws, size_t ws_size,
                              hipStream_t stream) {
  const float* x   = (const float*)d_in[0];
  const int*   ei  = (const int*)d_in[1];
  const float* W1l = (const float*)d_in[2];
  const float* W1r = (const float*)d_in[3];
  const float* b1  = (const float*)d_in[4];
  const float* W2l = (const float*)d_in[5];
  const float* W2r = (const float*)d_in[6];
  const float* b2  = (const float*)d_in[7];
  const float* W3l = (const float*)d_in[8];
  const float* W3r = (const float*)d_in[9];
  const float* b3  = (const float*)d_in[10];

  const int N = in_sizes[0] / DIM;  // 100000
  const int E = in_sizes[1] / 2;    // 1600000
  const int* src = ei;
  const int* dst = ei + E;
  const int B = (N + 255) / 256;

  char* ws = (char*)d_ws;
  size_t off_b = 0;
  auto alloc = [&](size_t bytes) {
    void* p = ws + off_b;
    off_b = (off_b + bytes + 255) & ~(size_t)255;
    return p;
  };
  unsigned* deg     = (unsigned*)alloc((size_t)N * 4);
  unsigned* excl    = (unsigned*)alloc((size_t)N * 4);
  unsigned* partial = (unsigned*)alloc((size_t)B * 4);
  unsigned* offs    = (unsigned*)alloc((size_t)(N + 1) * 4);
  unsigned* rank    = (unsigned*)alloc((size_t)E * 4);
  int*      csr_src = (int*)alloc((size_t)E * 4);
  float*    dinv    = (float*)alloc((size_t)N * 4);
  ushort*   xH      = (ushort*)alloc((size_t)N * DIM * 2);
  ushort*   aggH    = (ushort*)alloc((size_t)N * DIM * 2);
  ushort*   wtabs   = (ushort*)alloc((size_t)8 * 16384 * 2);
  float*    y       = (float*)alloc((size_t)N * 4 * 4);

  // ---- fused prep: hist_rank || cast || wsplit ----
  const int H = (E + 255) / 256;                       // 6250
  const int C = (int)(((size_t)N * DIM / 4 + 255) / 256);  // 12500
  hipMemsetAsync(deg, 0, (size_t)N * 4, stream);
  prep_kernel<<<H + C + 256, 256, 0, stream>>>(dst, deg, rank, E, x, xH, (long)N * DIM,
                                               W1l, W1r, W2l, W2r, wtabs, H, C);

  // ---- scan + fill ----
  scan_block_kernel<<<B, 256, 0, stream>>>(deg, excl, partial, dinv, N);
  scan_partials_kernel<<<1, 256, 0, stream>>>(partial, B);
  add_offsets_kernel<<<(N + 256) / 256, 256, 0, stream>>>(excl, partial, offs, N, E);
  csr_fill_kernel<<<(E + 255) / 256, 256, 0, stream>>>(src, dst, rank, offs, csr_src, E);

  const ushort* W1lH = wtabs;           const ushort* W1lL = wtabs + 16384;
  const ushort* W1rH = wtabs + 32768;   const ushort* W1rL = wtabs + 49152;
  const ushort* W2lH = wtabs + 65536;   const ushort* W2lL = wtabs + 81920;
  const ushort* W2rH = wtabs + 98304;   const ushort* W2rL = wtabs + 114688;

  const int gemm_grid = (N + 127) / 128;
  const int gather_grid = (N + 3) / 4;  // one wave per node

  // ---- layer 1 (h1 in-place over xH) ----
  gather_wave_kernel<<<gather_grid, 256, 0, stream>>>(xH, csr_src, offs, dinv, aggH, N);
  sage_mfma_kernel<<<gemm_grid, 256, 0, stream>>>(aggH, xH, W1lH, W1lL, W1rH, W1rL, b1,
                                                  nullptr, nullptr, xH, nullptr, N);
  // ---- layer 2 (in-place; fused lin3 -> y) ----
  gather_wave_kernel<<<gather_grid, 256, 0, stream>>>(xH, csr_src, offs, dinv, aggH, N);
  sage_mfma_kernel<<<gemm_grid, 256, 0, stream>>>(aggH, xH, W2lH, W2lL, W2rH, W2rL, b2,
                                                  W3l, W3r, xH, y, N);
  // ---- layer 3 ----
  final3_kernel<<<(N + 255) / 256, 256, 0, stream>>>(y, csr_src, offs, dinv, b3, (float*)d_out, N);
}

// Round 9
// 406.885 us; speedup vs baseline: 1.4694x; 1.0393x over previous
//
#include <hip/hip_runtime.h>
#include <hip/hip_bf16.h>
#include <math.h>

#define DIM 128

typedef __attribute__((ext_vector_type(8))) short bf16x8;
typedef __attribute__((ext_vector_type(4))) float f32x4;

__device__ __forceinline__ ushort f2bf(float f) {  // RTNE
  unsigned u = __float_as_uint(f);
  return (ushort)((u + 0x7FFFu + ((u >> 16) & 1u)) >> 16);
}
__device__ __forceinline__ float bf2f(ushort h) {
  return __uint_as_float(((unsigned)h) << 16);
}

// ---------------- fused prep: hist_rank || cast || wsplit, INTERLEAVED ----------------
// bid%3==0 -> hist (atomic-bound, memory-side atomic unit); other two thirds -> cast/wsplit
// (streaming) so they run in the hist waves' atomic-wait bubbles instead of after them.
__global__ __launch_bounds__(256) void prep_kernel(
    const int* __restrict__ dst, unsigned* __restrict__ deg, unsigned* __restrict__ rank, int E,
    const float* __restrict__ x, ushort* __restrict__ xh, long total,
    const float* __restrict__ W1l, const float* __restrict__ W1r,
    const float* __restrict__ W2l, const float* __restrict__ W2r,
    ushort* __restrict__ tabs, int H, int C) {
  const int bid = blockIdx.x;
  const int r = bid % 3;
  const int q = bid / 3;
  if (r == 0) {
    if (q < H) {
      int gid = q * 256 + threadIdx.x;
      if (gid < E) rank[gid] = atomicAdd(&deg[dst[gid]], 1u);
    }
    return;
  }
  int id2 = q * 2 + (r - 1);
  if (id2 < C) {
    long i = ((long)id2 * 256 + threadIdx.x) * 4;
    if (i >= total) return;
    float4 v = *(const float4*)(x + i);
    uint2 Hh;
    Hh.x = (unsigned)f2bf(v.x) | ((unsigned)f2bf(v.y) << 16);
    Hh.y = (unsigned)f2bf(v.z) | ((unsigned)f2bf(v.w) << 16);
    *(uint2*)(xh + i) = Hh;
    return;
  }
  id2 -= C;
  if (id2 >= 256) return;
  int m = id2 >> 6;
  const float* W = (m == 0) ? W1l : (m == 1) ? W1r : (m == 2) ? W2l : W2r;
  ushort* Ht = tabs + (size_t)m * 32768;
  ushort* Lt = Ht + 16384;
  int idx = (id2 & 63) * 256 + threadIdx.x;  // 0..16383
  int k = idx >> 7, n = idx & 127;
  float v = W[idx];
  ushort h = f2bf(v);
  Ht[n * DIM + k] = h;
  Lt[n * DIM + k] = f2bf(v - bf2f(h));
}

// ---------------- two-level exclusive scan over deg (+ fused dinv) ----------------
__global__ __launch_bounds__(256) void scan_block_kernel(const unsigned* __restrict__ deg,
                                                         unsigned* __restrict__ excl,
                                                         unsigned* __restrict__ partial,
                                                         float* __restrict__ dinv, int N) {
  __shared__ unsigned s[256];
  int i = blockIdx.x * 256 + threadIdx.x;
  unsigned v = (i < N) ? deg[i] : 0u;
  if (i < N) dinv[i] = 1.0f / fmaxf((float)v, 1.0f);
  s[threadIdx.x] = v;
  __syncthreads();
#pragma unroll
  for (int d = 1; d < 256; d <<= 1) {
    unsigned t = (threadIdx.x >= d) ? s[threadIdx.x - d] : 0u;
    __syncthreads();
    s[threadIdx.x] += t;
    __syncthreads();
  }
  if (i < N) excl[i] = s[threadIdx.x] - v;
  if (threadIdx.x == 255) partial[blockIdx.x] = s[255];
}

__global__ __launch_bounds__(256) void scan_partials_kernel(unsigned* __restrict__ partial, int B) {
  __shared__ unsigned s[256];
  __shared__ unsigned carry;
  if (threadIdx.x == 0) carry = 0u;
  __syncthreads();
  for (int base = 0; base < B; base += 256) {
    int i = base + threadIdx.x;
    unsigned v = (i < B) ? partial[i] : 0u;
    s[threadIdx.x] = v;
    __syncthreads();
#pragma unroll
    for (int d = 1; d < 256; d <<= 1) {
      unsigned t = (threadIdx.x >= d) ? s[threadIdx.x - d] : 0u;
      __syncthreads();
      s[threadIdx.x] += t;
      __syncthreads();
    }
    if (i < B) partial[i] = carry + s[threadIdx.x] - v;
    __syncthreads();
    if (threadIdx.x == 0) carry += s[255];
    __syncthreads();
  }
}

__global__ __launch_bounds__(256) void add_offsets_kernel(const unsigned* __restrict__ excl,
                                                          const unsigned* __restrict__ partial,
                                                          unsigned* __restrict__ off, int N, int E) {
  int i = blockIdx.x * 256 + threadIdx.x;
  if (i < N) off[i] = excl[i] + partial[i >> 8];
  if (i == N) off[N] = (unsigned)E;
}

// ---------------- CSR fill: atomic-free ----------------
__global__ __launch_bounds__(256) void csr_fill_kernel(const int* __restrict__ src,
                                                       const int* __restrict__ dst,
                                                       const unsigned* __restrict__ rank,
                                                       const unsigned* __restrict__ off,
                                                       int* __restrict__ csr_src, int E) {
  int e = blockIdx.x * 256 + threadIdx.x;
  if (e >= E) return;
  csr_src[off[dst[e]] + rank[e]] = src[e];
}

// ---------------- wave-per-node gather-aggregate (hi only) ----------------
// 64 lanes = 4 edge-slots x 16 cols x 16 B; 16 edges per main iter -> 4 independent
// feature-row loads in flight per lane.
__global__ __launch_bounds__(256) void gather_wave_kernel(
    const ushort* __restrict__ featH, const int* __restrict__ csr_src,
    const unsigned* __restrict__ off, const float* __restrict__ dinv,
    ushort* __restrict__ aggH, int N) {
  const int node = (blockIdx.x * 256 + threadIdx.x) >> 6;
  if (node >= N) return;
  const int lane = threadIdx.x & 63;
  const int eslot = lane >> 4;
  const int col = lane & 15;
  const unsigned beg = off[node], end = off[node + 1];
  const ushort* fbase = featH + col * 8;

  float acc[8];
#pragma unroll
  for (int t = 0; t < 8; ++t) acc[t] = 0.f;

  auto accum = [&](int4 v) {
    unsigned w0 = (unsigned)v.x, w1 = (unsigned)v.y, w2 = (unsigned)v.z, w3 = (unsigned)v.w;
    acc[0] += __uint_as_float(w0 << 16);
    acc[1] += __uint_as_float(w0 & 0xFFFF0000u);
    acc[2] += __uint_as_float(w1 << 16);
    acc[3] += __uint_as_float(w1 & 0xFFFF0000u);
    acc[4] += __uint_as_float(w2 << 16);
    acc[5] += __uint_as_float(w2 & 0xFFFF0000u);
    acc[6] += __uint_as_float(w3 << 16);
    acc[7] += __uint_as_float(w3 & 0xFFFF0000u);
  };

  unsigned base = beg;
  for (; base + 16 <= end; base += 16) {
    int s0 = csr_src[base + eslot];
    int s1 = csr_src[base + 4 + eslot];
    int s2 = csr_src[base + 8 + eslot];
    int s3 = csr_src[base + 12 + eslot];
    int4 v0 = *(const int4*)(fbase + (size_t)s0 * DIM);
    int4 v1 = *(const int4*)(fbase + (size_t)s1 * DIM);
    int4 v2 = *(const int4*)(fbase + (size_t)s2 * DIM);
    int4 v3 = *(const int4*)(fbase + (size_t)s3 * DIM);
    accum(v0); accum(v1); accum(v2); accum(v3);
  }
  for (; base + 8 <= end; base += 8) {
    int s0 = csr_src[base + eslot];
    int s1 = csr_src[base + 4 + eslot];
    int4 v0 = *(const int4*)(fbase + (size_t)s0 * DIM);
    int4 v1 = *(const int4*)(fbase + (size_t)s1 * DIM);
    accum(v0); accum(v1);
  }
  for (unsigned e = base + eslot; e < end; e += 4) {
    int s = csr_src[e];
    int4 v = *(const int4*)(fbase + (size_t)s * DIM);
    accum(v);
  }

#pragma unroll
  for (int t = 0; t < 8; ++t) {
    acc[t] += __shfl_xor(acc[t], 32, 64);
    acc[t] += __shfl_xor(acc[t], 16, 64);
  }

  if (eslot == 0) {
    float di = dinv[node];
    unsigned ph[4];
#pragma unroll
    for (int t = 0; t < 4; ++t) {
      ph[t] = (unsigned)f2bf(acc[2 * t] * di) | ((unsigned)f2bf(acc[2 * t + 1] * di) << 16);
    }
    *(int4*)(aggH + (size_t)node * DIM + col * 8) =
        make_int4((int)ph[0], (int)ph[1], (int)ph[2], (int)ph[3]);
  }
}

// ---------------- MFMA SAGE layer (optional fused lin3 -> y) ----------------
// out = relu( aggH@(WlH+WlL) + xH@(WrH+WrL) + b ).
// 4 stage rounds (A-tile staged ONCE, both weight tiles H+L resident in a 32 KB Bs),
// 64 MFMA per barrier. Epilogue Wc/Yp alias the dead As region -> LDS 48 KB.
__global__ __launch_bounds__(256) void sage_mfma_kernel(
    const ushort* __restrict__ aggH, const ushort* xH,
    const ushort* __restrict__ WlH, const ushort* __restrict__ WlL,
    const ushort* __restrict__ WrH, const ushort* __restrict__ WrL,
    const float* __restrict__ bias,
    const float* __restrict__ W3l, const float* __restrict__ W3r,
    ushort* outH, float* __restrict__ y, int N) {
  __shared__ ushort As[128 * 64];      // 16 KB
  __shared__ ushort Bs[2 * 128 * 64];  // 32 KB: [0]=W_H tile, [1]=W_L tile

  const int tid = threadIdx.x;
  const int bm = blockIdx.x * 128;
  const int wave = tid >> 6;
  const int lane = tid & 63;
  const int l15 = lane & 15;
  const int quad = lane >> 4;
  const int wm = wave >> 1;
  const int wn = wave & 1;

  f32x4 acc[4][4];
#pragma unroll
  for (int i = 0; i < 4; ++i)
#pragma unroll
    for (int j = 0; j < 4; ++j) acc[i][j] = (f32x4){0.f, 0.f, 0.f, 0.f};

  for (int g = 0; g < 4; ++g) {
    const ushort* Ap = (g < 2) ? aggH : xH;
    const ushort* WH = (g < 2) ? WlH : WrH;
    const ushort* WL = (g < 2) ? WlL : WrL;
    const int kt = (g & 1) << 6;
    __syncthreads();
    // stage A tile: 128 rows x 64 k
#pragma unroll
    for (int c = 0; c < 4; ++c) {
      int flat = c * 256 + tid;
      int row = flat >> 3;
      int kg = flat & 7;
      int swz = (kg ^ (row & 7)) << 3;
      int grow = bm + row;
      if (grow >= N) grow = N - 1;
      *(int4*)(&As[row * 64 + swz]) = *(const int4*)(Ap + (size_t)grow * DIM + kt + kg * 8);
    }
    // stage both weight tiles (H then L)
#pragma unroll
    for (int c = 0; c < 8; ++c) {
      int flat = c * 256 + tid;          // 0..2047
      int tbl = flat >> 10;
      int row = (flat >> 3) & 127;
      int kg = flat & 7;
      int swz = (kg ^ (row & 7)) << 3;
      const ushort* Wp = tbl ? WL : WH;
      *(int4*)(&Bs[tbl * 8192 + row * 64 + swz]) =
          *(const int4*)(Wp + (size_t)row * DIM + kt + kg * 8);
    }
    __syncthreads();
#pragma unroll
    for (int ks = 0; ks < 2; ++ks) {
      bf16x8 af[4], bh[4], bl[4];
      int kg = (ks << 2) + quad;
#pragma unroll
      for (int i = 0; i < 4; ++i) {
        int ar = (wm << 6) + (i << 4) + l15;
        af[i] = *(const bf16x8*)(&As[ar * 64 + ((kg ^ (ar & 7)) << 3)]);
        int br = (wn << 6) + (i << 4) + l15;
        int bo = br * 64 + ((kg ^ (br & 7)) << 3);
        bh[i] = *(const bf16x8*)(&Bs[bo]);
        bl[i] = *(const bf16x8*)(&Bs[8192 + bo]);
      }
#pragma unroll
      for (int i = 0; i < 4; ++i)
#pragma unroll
        for (int j = 0; j < 4; ++j) {
          acc[i][j] = __builtin_amdgcn_mfma_f32_16x16x32_bf16(af[i], bh[j], acc[i][j], 0, 0, 0);
          acc[i][j] = __builtin_amdgcn_mfma_f32_16x16x32_bf16(af[i], bl[j], acc[i][j], 0, 0, 0);
        }
    }
  }

  __syncthreads();  // As/Bs dead; safe to alias epilogue buffers onto As
  float* WcF = reinterpret_cast<float*>(As);        // [128][4] = 2 KB
  float* YpF = reinterpret_cast<float*>(As) + 512;  // [128][4][2] = 4 KB

  if (W3l) {
    // 512 floats from 256 threads: STRIDED (R8 bug: `if (tid<512)` only wrote 256)
    for (int t = tid; t < 512; t += 256) {
      int col = t >> 2, c = t & 3;
      WcF[t] = (c < 2) ? W3l[col * 2 + c] : W3r[col * 2 + (c - 2)];
    }
    __syncthreads();
  }

  float bv[4];
#pragma unroll
  for (int j = 0; j < 4; ++j) bv[j] = bias[(wn << 6) + (j << 4) + l15];

#pragma unroll
  for (int i = 0; i < 4; ++i) {
#pragma unroll
    for (int r = 0; r < 4; ++r) {
      const int rowl = (wm << 6) + (i << 4) + (quad << 2) + r;
      const int grow = bm + rowl;
      float p0 = 0.f, p1 = 0.f, p2 = 0.f, p3 = 0.f;
#pragma unroll
      for (int j = 0; j < 4; ++j) {
        float v = fmaxf(acc[i][j][r] + bv[j], 0.f);
        ushort h = f2bf(v);
        if (grow < N) outH[(size_t)grow * DIM + (wn << 6) + (j << 4) + l15] = h;
        if (W3l) {
          float qv = bf2f(h);  // match bf16-rounded h exactly
          int col = (wn << 6) + (j << 4) + l15;
          p0 += qv * WcF[col * 4 + 0];
          p1 += qv * WcF[col * 4 + 1];
          p2 += qv * WcF[col * 4 + 2];
          p3 += qv * WcF[col * 4 + 3];
        }
      }
      if (W3l) {
#pragma unroll
        for (int o = 1; o < 16; o <<= 1) {
          p0 += __shfl_xor(p0, o, 64);
          p1 += __shfl_xor(p1, o, 64);
          p2 += __shfl_xor(p2, o, 64);
          p3 += __shfl_xor(p3, o, 64);
        }
        if (l15 == 0) {
          YpF[(rowl * 4 + 0) * 2 + wn] = p0;
          YpF[(rowl * 4 + 1) * 2 + wn] = p1;
          YpF[(rowl * 4 + 2) * 2 + wn] = p2;
          YpF[(rowl * 4 + 3) * 2 + wn] = p3;
        }
      }
    }
  }

  if (W3l) {
    __syncthreads();
    for (int t = tid; t < 512; t += 256) {
      int grow = bm + (t >> 2);
      if (grow < N) y[(size_t)grow * 4 + (t & 3)] = YpF[t * 2 + 0] + YpF[t * 2 + 1];
    }
  }
}

// ---------------- layer 3: 2-dim CSR gather + bias + relu + log_softmax ----------------
__global__ __launch_bounds__(256) void final3_kernel(const float* __restrict__ y,
                                                     const int* __restrict__ csr_src,
                                                     const unsigned* __restrict__ off,
                                                     const float* __restrict__ dinv,
                                                     const float* __restrict__ b3,
                                                     float* __restrict__ out, int N) {
  int n = blockIdx.x * 256 + threadIdx.x;
  if (n >= N) return;
  unsigned beg = off[n], end = off[n + 1];
  float s0 = 0.f, s1 = 0.f;
  for (unsigned e = beg; e < end; ++e) {
    int s = csr_src[e];
    float2 v = *reinterpret_cast<const float2*>(&y[(size_t)s * 4]);
    s0 += v.x; s1 += v.y;
  }
  float di = dinv[n];
  float o0 = fmaxf(s0 * di + y[(size_t)n * 4 + 2] + b3[0], 0.f);
  float o1 = fmaxf(s1 * di + y[(size_t)n * 4 + 3] + b3[1], 0.f);
  float m = fmaxf(o0, o1);
  float l = m + logf(expf(o0 - m) + expf(o1 - m));
  out[n * 2 + 0] = o0 - l;
  out[n * 2 + 1] = o1 - l;
}

extern "C" void kernel_launch(void* const* d_in, const int* in_sizes, int n_in,
                              void* d_out, int out_size, void* d_ws, size_t ws_size,
                              hipStream_t stream) {
  const float* x   = (const float*)d_in[0];
  const int*   ei  = (const int*)d_in[1];
  const float* W1l = (const float*)d_in[2];
  const float* W1r = (const float*)d_in[3];
  const float* b1  = (const float*)d_in[4];
  const float* W2l = (const float*)d_in[5];
  const float* W2r = (const float*)d_in[6];
  const float* b2  = (const float*)d_in[7];
  const float* W3l = (const float*)d_in[8];
  const float* W3r = (const float*)d_in[9];
  const float* b3  = (const float*)d_in[10];

  const int N = in_sizes[0] / DIM;  // 100000
  const int E = in_sizes[1] / 2;    // 1600000
  const int* src = ei;
  const int* dst = ei + E;
  const int B = (N + 255) / 256;

  char* ws = (char*)d_ws;
  size_t off_b = 0;
  auto alloc = [&](size_t bytes) {
    void* p = ws + off_b;
    off_b = (off_b + bytes + 255) & ~(size_t)255;
    return p;
  };
  unsigned* deg     = (unsigned*)alloc((size_t)N * 4);
  unsigned* excl    = (unsigned*)alloc((size_t)N * 4);
  unsigned* partial = (unsigned*)alloc((size_t)B * 4);
  unsigned* offs    = (unsigned*)alloc((size_t)(N + 1) * 4);
  unsigned* rank    = (unsigned*)alloc((size_t)E * 4);
  int*      csr_src = (int*)alloc((size_t)E * 4);
  float*    dinv    = (float*)alloc((size_t)N * 4);
  ushort*   xH      = (ushort*)alloc((size_t)N * DIM * 2);
  ushort*   aggH    = (ushort*)alloc((size_t)N * DIM * 2);
  ushort*   wtabs   = (ushort*)alloc((size_t)8 * 16384 * 2);
  float*    y       = (float*)alloc((size_t)N * 4 * 4);

  // ---- fused prep: hist_rank || cast || wsplit, interleaved ----
  const int H = (E + 255) / 256;                           // 6250
  const int C = (int)(((size_t)N * DIM / 4 + 255) / 256);  // 12500
  const int third = (H > (C + 257) / 2) ? H : (C + 257) / 2;
  hipMemsetAsync(deg, 0, (size_t)N * 4, stream);
  prep_kernel<<<third * 3, 256, 0, stream>>>(dst, deg, rank, E, x, xH, (long)N * DIM,
                                             W1l, W1r, W2l, W2r, wtabs, H, C);

  // ---- scan + fill ----
  scan_block_kernel<<<B, 256, 0, stream>>>(deg, excl, partial, dinv, N);
  scan_partials_kernel<<<1, 256, 0, stream>>>(partial, B);
  add_offsets_kernel<<<(N + 256) / 256, 256, 0, stream>>>(excl, partial, offs, N, E);
  csr_fill_kernel<<<(E + 255) / 256, 256, 0, stream>>>(src, dst, rank, offs, csr_src, E);

  const ushort* W1lH = wtabs;           const ushort* W1lL = wtabs + 16384;
  const ushort* W1rH = wtabs + 32768;   const ushort* W1rL = wtabs + 49152;
  const ushort* W2lH = wtabs + 65536;   const ushort* W2lL = wtabs + 81920;
  const ushort* W2rH = wtabs + 98304;   const ushort* W2rL = wtabs + 114688;

  const int gemm_grid = (N + 127) / 128;
  const int gather_grid = (N + 3) / 4;  // one wave per node

  // ---- layer 1 (h1 in-place over xH) ----
  gather_wave_kernel<<<gather_grid, 256, 0, stream>>>(xH, csr_src, offs, dinv, aggH, N);
  sage_mfma_kernel<<<gemm_grid, 256, 0, stream>>>(aggH, xH, W1lH, W1lL, W1rH, W1rL, b1,
                                                  nullptr, nullptr, xH, nullptr, N);
  // ---- layer 2 (in-place; fused lin3 -> y) ----
  gather_wave_kernel<<<gather_grid, 256, 0, stream>>>(xH, csr_src, offs, dinv, aggH, N);
  sage_mfma_kernel<<<gemm_grid, 256, 0, stream>>>(aggH, xH, W2lH, W2lL, W2rH, W2rL, b2,
                                                  W3l, W3r, xH, y, N);
  // ---- layer 3 ----
  final3_kernel<<<(N + 255) / 256, 256, 0, stream>>>(y, csr_src, offs, dinv, b3, (float*)d_out, N);
}